// Round 13
// baseline (42.034 us; speedup 1.0000x reference)
//
#include <hip/hip_runtime.h>
#include <cstdint>
#include <cstddef>

#define BS 8
#define NQ 16384
#define NG 1024
#define NC 5
#define SHARDS 32           // shards per batch; k1 grid = BS*SHARDS = 256 blocks
#define SQ 512              // queries per shard
#define CAPC 192            // per-class LDS candidate list capacity
#define SLACK 0.1514214f    // 0.1*sqrt(2) + 0.01 fp margin
#define FINF 3.0e38f

using u64 = unsigned long long;
typedef unsigned int u32;

// ---------- float top-4 (keep 4 smallest, sorted ascending) ----------
__device__ __forceinline__ void fce(float &x, float &y) {
    float lo = fminf(x, y), hi = fmaxf(x, y);
    x = lo; y = hi;
}
__device__ __forceinline__ void finsert(float k[4], float v) {
    float c = v, t;
    t = fminf(k[0], c); c = fmaxf(k[0], c); k[0] = t;
    t = fminf(k[1], c); c = fmaxf(k[1], c); k[1] = t;
    t = fminf(k[2], c); c = fmaxf(k[2], c); k[2] = t;
    k[3] = fminf(k[3], c);
}
__device__ __forceinline__ void fmerge4(float a[4], float b0, float b1, float b2, float b3) {
    float m0 = fminf(a[0], b3), m1 = fminf(a[1], b2), m2 = fminf(a[2], b1), m3 = fminf(a[3], b0);
    fce(m0, m2); fce(m1, m3); fce(m0, m1); fce(m2, m3);
    a[0] = m0; a[1] = m1; a[2] = m2; a[3] = m3;
}

// ---------- u64 keyed top-4 (exact, tie-break by low 32 = q) ----------
__device__ __forceinline__ void ce(u64 &x, u64 &y) {
    u64 lo = x < y ? x : y;
    u64 hi = x < y ? y : x;
    x = lo; y = hi;
}
__device__ __forceinline__ void kinsert_key(u64 kk[4], u64 k) {
    if (k < kk[3]) { kk[3] = k; ce(kk[2], kk[3]); ce(kk[1], kk[2]); ce(kk[0], kk[1]); }
}
__device__ __forceinline__ void kinsert(u64 kk[4], float cost, unsigned q) {
    unsigned uu = __float_as_uint(cost);
    uu ^= ((unsigned)((int)uu >> 31)) | 0x80000000u;
    kinsert_key(kk, ((u64)uu << 32) | q);
}

// exact softmax numerics — identical to all prior passing rounds
#define SOFTMAX5(lg, X0, X1, X2, X3, X4, S)                                     \
    float X0 = (lg)[0], X1 = (lg)[1], X2 = (lg)[2], X3 = (lg)[3], X4 = (lg)[4]; \
    {                                                                           \
        float mx_ = fmaxf(fmaxf(fmaxf(X0, X1), fmaxf(X2, X3)), X4);             \
        X0 = expf(X0 - mx_); X1 = expf(X1 - mx_); X2 = expf(X2 - mx_);          \
        X3 = expf(X3 - mx_); X4 = expf(X4 - mx_);                               \
    }                                                                           \
    float S = X0 + X1 + X2 + X3 + X4;

// k1: one block = (batch b, shard of SQ queries). ALL math exact (no fast paths).
//  P1: tid<SQ computes the 5 exact probs of its query -> LDS probs[c][SQ].
//  P2: waves 0..4 reduce shard-local per-class top-4 -> T_c = localP4 - SLACK.
//  P3: tid<SQ ballot-appends (prob,q) to lists[c] for p>=T_c (>=4 guaranteed).
//  P4: thread=gt: partial keyed top-4 over lists[label] (or all SQ shard probs
//      if CAPC overflowed), written to part_out[b][g][shard][4].
// Shard-local prune validity (R6 argument): a global-top-4 query q* in this
// shard has cost <= global-4th <= shard-4th <= 0.1*sqrt(2) - localP4
// => p_c(q*) >= localP4 - 0.1*sqrt(2) > T_c. Merge of per-shard exact top-4s
// over all shards = exact global top-4 (keys totally ordered, q in low bits).
__global__ __launch_bounds__(1024, 1) void shard_kernel(
        const float* __restrict__ pred_coords,   // [BS][NQ][2]
        const float* __restrict__ logits,        // [BS][NQ][NC]
        const float* __restrict__ gt_coords,     // [BS][NG][2]
        const int*   __restrict__ gt_labels,     // [BS][NG]
        const int*   __restrict__ gt_masks,      // [BS][NG]
        u64*         __restrict__ part_out)      // [BS][NG][SHARDS][4]
{
    const int tid = threadIdx.x;
    const int wv = tid >> 6, lane = tid & 63;
    const int b = blockIdx.x / SHARDS, part = blockIdx.x % SHARDS;
    const int q0 = part * SQ;

    __shared__ float probs[NC][SQ];              // 10 KB
    __shared__ u64   lists[NC][CAPC];            // 7.5 KB
    __shared__ float Tsh[NC];
    __shared__ u32   lcount[NC];
    __shared__ u32   ovfl;

    if (tid == 0) ovfl = 0u;
    if (tid < NC) lcount[tid] = 0u;

    // ---- P1: exact probs (one query per thread, tid < SQ) ----
    float p_reg[NC] = {0.f, 0.f, 0.f, 0.f, 0.f};
    if (tid < SQ) {
        const float* lg = logits + ((size_t)b * NQ + q0 + tid) * NC;
        SOFTMAX5(lg, x0, x1, x2, x3, x4, s);
        p_reg[0] = x0 / s; p_reg[1] = x1 / s; p_reg[2] = x2 / s;
        p_reg[3] = x3 / s; p_reg[4] = x4 / s;
        #pragma unroll
        for (int c = 0; c < NC; ++c) probs[c][tid] = p_reg[c];
    }
    __syncthreads();

    // ---- P2: shard-local per-class top-4 -> threshold (waves 0..4) ----
    if (wv < NC) {
        float t4[4] = {FINF, FINF, FINF, FINF};
        #pragma unroll
        for (int i = 0; i < SQ / 64; ++i) finsert(t4, -probs[wv][i * 64 + lane]);
        #pragma unroll
        for (int d = 1; d < 64; d <<= 1) {
            float b0 = __shfl_xor(t4[0], d, 64);
            float b1 = __shfl_xor(t4[1], d, 64);
            float b2 = __shfl_xor(t4[2], d, 64);
            float b3 = __shfl_xor(t4[3], d, 64);
            fmerge4(t4, b0, b1, b2, b3);
        }
        if (lane == 0) Tsh[wv] = -t4[3] - SLACK;     // localP4 - SLACK
    }
    __syncthreads();

    // ---- P3: ballot-append candidates (tid < SQ) ----
    if (tid < SQ) {
        #pragma unroll
        for (int c = 0; c < NC; ++c) {
            bool pass = (p_reg[c] >= Tsh[c]);
            u64 mk = __ballot(pass);
            if (mk) {
                u32 base = 0;
                if (lane == 0) base = atomicAdd(&lcount[c], (u32)__popcll(mk));
                base = __shfl((int)base, 0, 64);
                if (pass) {
                    u32 r = base + (u32)__popcll(mk & ((1ull << lane) - 1ull));
                    if (r < CAPC)
                        lists[c][r] = ((u64)__float_as_uint(p_reg[c]) << 32) | (u32)(q0 + tid);
                }
            }
        }
    }
    __syncthreads();
    if (tid < NC && lcount[tid] > CAPC) atomicOr(&ovfl, 1u << tid);
    __syncthreads();

    // ---- P4: per-gt partial keyed top-4 over this shard (thread = gt) ----
    {
        const int g = tid;
        const int m = gt_masks[b * NG + g];
        if (m) {
            int c = gt_labels[b * NG + g];
            float2 gc = reinterpret_cast<const float2*>(gt_coords)[(size_t)b * NG + g];
            float gx = gc.x, gy = gc.y, gb2 = gc.x * gc.x + gc.y * gc.y;
            const float2* pc = reinterpret_cast<const float2*>(pred_coords) + (size_t)b * NQ;
            u64 kk[4] = {~0ull, ~0ull, ~0ull, ~0ull};
            if (!((ovfl >> c) & 1u)) {
                u32 nn = lcount[c];                  // <= CAPC, >= 4
                for (u32 j = 0; j < nn; ++j) {
                    u64 e = lists[c][j];
                    float p = __uint_as_float((u32)(e >> 32));
                    u32 qq = (u32)(e & 0xFFFFFFFFu);
                    float2 cq = pc[qq];
                    float d2 = fmaxf(cq.x * cq.x + cq.y * cq.y + gb2
                                     - 2.0f * (cq.x * gx + cq.y * gy), 0.0f);
                    kinsert(kk, 0.1f * sqrtf(d2) - p, qq);
                }
            } else {
                // overflow fallback: scan ALL shard probs from LDS (still exact)
                for (int j = 0; j < SQ; ++j) {
                    float p = probs[c][j];
                    u32 qq = (u32)(q0 + j);
                    float2 cq = pc[qq];
                    float d2 = fmaxf(cq.x * cq.x + cq.y * cq.y + gb2
                                     - 2.0f * (cq.x * gx + cq.y * gy), 0.0f);
                    kinsert(kk, 0.1f * sqrtf(d2) - p, qq);
                }
            }
            u64* dst = part_out + (((size_t)((b << 10) | g)) * SHARDS + part) * 4;
            dst[0] = kk[0]; dst[1] = kk[1]; dst[2] = kk[2]; dst[3] = kk[3];
        }
    }
}

// k2: per gt, merge the 32 shards' sorted top-4s (128 contiguous u64 = 1 KB).
__global__ __launch_bounds__(256) void merge_kernel(
        const int* __restrict__ gt_masks,        // [BS][NG]
        const u64* __restrict__ part_out,        // [BS][NG][SHARDS][4]
        int*       __restrict__ out)             // [BS][4][NG]
{
    const int idx = blockIdx.x * 256 + threadIdx.x;  // 8192 gts
    const int b = idx >> 10, g = idx & 1023;
    const int m = gt_masks[idx];
    u64 kk[4] = {~0ull, ~0ull, ~0ull, ~0ull};
    if (m) {
        const ulonglong2* p2 = reinterpret_cast<const ulonglong2*>(
            part_out + (size_t)idx * SHARDS * 4);
        #pragma unroll 8
        for (int j = 0; j < SHARDS * 2; ++j) {       // 64 x 16B vector loads
            ulonglong2 v = p2[j];
            kinsert_key(kk, v.x);
            kinsert_key(kk, v.y);
        }
    }
    #pragma unroll
    for (int j = 0; j < 4; ++j)
        out[((size_t)(b * 4 + j) << 10) + g] = m ? (int)(kk[j] & 0xFFFFFFFFull) : j;
}

extern "C" void kernel_launch(void* const* d_in, const int* in_sizes, int n_in,
                              void* d_out, int out_size, void* d_ws, size_t ws_size,
                              hipStream_t stream) {
    const float* pred_coords = (const float*)d_in[0];
    const float* pred_logits = (const float*)d_in[1];
    const float* gt_coords   = (const float*)d_in[2];
    const int*   gt_labels   = (const int*)d_in[3];
    const int*   gt_masks    = (const int*)d_in[4];
    int* out = (int*)d_out;

    u64* part_out = (u64*)d_ws;   // BS*NG*SHARDS*4*8 = 8.39 MB; every read slot
                                  // is written by k1 in the same call (masked
                                  // slots are never read) -> no memset needed.

    shard_kernel<<<BS * SHARDS, 1024, 0, stream>>>(
        pred_coords, pred_logits, gt_coords, gt_labels, gt_masks, part_out);
    merge_kernel<<<BS * NG / 256, 256, 0, stream>>>(gt_masks, part_out, out);
}